// Round 8
// baseline (169.090 us; speedup 1.0000x reference)
//
#include <hip/hip_runtime.h>
#include <math.h>

typedef __attribute__((ext_vector_type(8))) short bf16x8;
typedef __attribute__((ext_vector_type(4))) float f32x4;
typedef __attribute__((ext_vector_type(4))) unsigned short u16x4;

#define B_    2
#define T_    2048
#define DIM_  1024
#define H_    16
#define KV_   4
#define HD_   64

// 1/sqrt(HD) * log2(e): folded into Q at projection time -> S is exp2-domain
#define QSCALE 0.1803368801111437f

static __device__ __forceinline__ unsigned short f2bf(float f) {
    union { float f; unsigned int u; } v; v.f = f;
    unsigned int r = v.u + 0x7fff + ((v.u >> 16) & 1);   // RNE
    return (unsigned short)(r >> 16);
}

static __device__ __forceinline__ void gload16(const void* g, void* l) {
    __builtin_amdgcn_global_load_lds(
        (const __attribute__((address_space(1))) unsigned int*)g,
        (__attribute__((address_space(3))) unsigned int*)l, 16, 0, 0);
}

// Workspace (unsigned short elements):
//   xb   bf16 [4096][1024]          off 0
//   Wt   bf16 [1536][1024]          off 4194304   (Wq^T | Wk^T | Wv^T rows)
//   Wot  bf16 [1024][1024]          off 5767168
//   Q    bf16 [B][H][T][64]         off 6815744   (row-major, PRE-SCALED by QSCALE)
//   K    bf16 [B][KV][T][64]        off 11010048  (XOR-swizzled rows: 2d ^ ((t&7)<<4))
//   Vt   bf16 [B][KV][64][T]        off 12058624  (XOR-swizzled: 2t ^ ((d&7)<<4))
//   attnb bf16 [B][T][DIM]          off 13107200
#define XB_OFF   0u
#define WT_OFF   4194304u
#define WOT_OFF  5767168u
#define QB_OFF   6815744u
#define KB_OFF   11010048u
#define VTB_OFF  12058624u
#define AB_OFF   13107200u

// ---------------------------------------------------------------------------
// Pre-pass: f32 -> bf16 convert (8 elems/thread)
// ---------------------------------------------------------------------------
__global__ __launch_bounds__(256) void cvt_kernel(
    const float* __restrict__ in, unsigned short* __restrict__ out)
{
    const size_t i = ((size_t)blockIdx.x * 256 + threadIdx.x) * 8;
    float4 a = *(const float4*)&in[i];
    float4 b = *(const float4*)&in[i + 4];
    unsigned short u[8] = {f2bf(a.x), f2bf(a.y), f2bf(a.z), f2bf(a.w),
                           f2bf(b.x), f2bf(b.y), f2bf(b.z), f2bf(b.w)};
    *(bf16x8*)&out[i] = *(bf16x8*)u;
}

// ---------------------------------------------------------------------------
// Pre-pass: W f32 [1024][N] -> Wt bf16 [N][1024]  (64x64 LDS tile transpose)
// ---------------------------------------------------------------------------
__global__ __launch_bounds__(256) void wtrans_kernel(
    const float* __restrict__ W, unsigned short* __restrict__ Wt, int N)
{
    __shared__ float Ts[64][65];
    const int n0 = blockIdx.x * 64, k0 = blockIdx.y * 64;
    const int tid = threadIdx.x;
    const int r = tid >> 4, c4 = (tid & 15) * 4;
    #pragma unroll
    for (int i = 0; i < 4; ++i) {
        float4 v = *(const float4*)&W[(size_t)(k0 + r + 16 * i) * N + n0 + c4];
        Ts[r + 16 * i][c4 + 0] = v.x; Ts[r + 16 * i][c4 + 1] = v.y;
        Ts[r + 16 * i][c4 + 2] = v.z; Ts[r + 16 * i][c4 + 3] = v.w;
    }
    __syncthreads();
    const int rn = tid >> 3, ck = (tid & 7) * 8;
    #pragma unroll
    for (int i = 0; i < 2; ++i) {
        int n = rn + 32 * i;
        unsigned short u[8];
        #pragma unroll
        for (int e = 0; e < 8; ++e) u[e] = f2bf(Ts[ck + e][n]);
        *(bf16x8*)&Wt[(size_t)(n0 + n) * 1024 + k0 + ck] = *(bf16x8*)u;
    }
}

// ---------------------------------------------------------------------------
// Kernel 1: QKV bf16 MFMA GEMM + RoPE epilogue.
// C[4096][1536] = xb @ Wt^T. 128x128 tile, BK=64, 4 waves of 64x64.
// Q stores pre-scaled by QSCALE; K and Vt stored XOR-swizzled for attention's
// linear global_load_lds staging.
// ---------------------------------------------------------------------------
__global__ __launch_bounds__(256) void qkv_mfma_kernel(
    const unsigned short* __restrict__ xb, const unsigned short* __restrict__ Wt,
    const float* __restrict__ sinp, const float* __restrict__ cosp,
    unsigned short* __restrict__ Qw, unsigned short* __restrict__ Kw,
    unsigned short* __restrict__ Vtw)
{
    __shared__ __align__(16) unsigned char As[16384];   // [128 m][128B], XOR-swizzled
    __shared__ __align__(16) unsigned char Bs[16384];   // [128 n][128B]

    const int tid = threadIdx.x, lane = tid & 63, w = tid >> 6;
    const int lr = lane & 15, lg = lane >> 4;
    const int wm = w >> 1, wn = w & 1;
    const int bn = blockIdx.x, bm = blockIdx.y;
    const int m0 = bm * 128, n0 = bn * 128;

    const int chunkR = lane >> 3;                    // row within 8-row chunk
    const int srcOff = 8 * ((lane & 7) ^ chunkR);    // inverse-swizzled src (elems)

    f32x4 acc[4][4] = {};

    for (int k0 = 0; k0 < 1024; k0 += 64) {
        __syncthreads();
        #pragma unroll
        for (int i = 0; i < 4; ++i) {
            const int chunk = w * 4 + i;
            const int row = chunk * 8 + chunkR;
            gload16(xb + (size_t)(m0 + row) * 1024 + k0 + srcOff, As + chunk * 1024);
            gload16(Wt + (size_t)(n0 + row) * 1024 + k0 + srcOff, Bs + chunk * 1024);
        }
        __syncthreads();   // compiler drains vmcnt before s_barrier
        #pragma unroll
        for (int kk = 0; kk < 2; ++kk) {
            bf16x8 af[4], bfr[4];
            #pragma unroll
            for (int mf = 0; mf < 4; ++mf) {
                const int row = wm * 64 + mf * 16 + lr;
                af[mf] = *(const bf16x8*)(As + row * 128 +
                          ((kk * 64 + lg * 16) ^ ((row & 7) << 4)));
            }
            #pragma unroll
            for (int nf = 0; nf < 4; ++nf) {
                const int row = wn * 64 + nf * 16 + lr;
                bfr[nf] = *(const bf16x8*)(Bs + row * 128 +
                          ((kk * 64 + lg * 16) ^ ((row & 7) << 4)));
            }
            #pragma unroll
            for (int mf = 0; mf < 4; ++mf)
                #pragma unroll
                for (int nf = 0; nf < 4; ++nf)
                    acc[mf][nf] = __builtin_amdgcn_mfma_f32_16x16x32_bf16(
                        af[mf], bfr[nf], acc[mf][nf], 0, 0, 0);
        }
    }

    // Epilogue: C row m = m0+wm*64+mf*16+lg*4+r, col = n0+wn*64+nf*16+lr
    const float rsign = (lane & 1) ? 1.f : -1.f;
    #pragma unroll
    for (int nf = 0; nf < 4; ++nf) {
        const int col = n0 + wn * 64 + nf * 16 + lr;
        #pragma unroll
        for (int mf = 0; mf < 4; ++mf) {
            const int mrow = m0 + wm * 64 + mf * 16 + lg * 4;
            const int b = mrow >> 11;
            const int t0 = mrow & 2047;
            if (col < 1280) {   // Q or K: RoPE (block-uniform branch)
                const int d = col & 63;
                #pragma unroll
                for (int r = 0; r < 4; ++r) {
                    float val = acc[mf][nf][r];
                    float partner = __shfl_xor(val, 1);
                    const int t = t0 + r;
                    float cs = cosp[t * 64 + d], sn = sinp[t * 64 + d];
                    float rv = val * cs + rsign * partner * sn;
                    if (col < 1024) {
                        const int h = col >> 6;
                        Qw[(((size_t)b * H_ + h) * T_ + t) * 64 + d] =
                            f2bf(rv * QSCALE);
                    } else {
                        const int kv = (col - 1024) >> 6;
                        // swizzled store: byte = t*128 + (2d ^ ((t&7)<<4))
                        char* krow = (char*)Kw +
                            ((((size_t)b * KV_ + kv) * T_ + t) << 7);
                        *(unsigned short*)(krow + ((2 * d) ^ ((t & 7) << 4))) =
                            f2bf(rv);
                    }
                }
            } else {            // V: transposed swizzled store, 4 t packed (8B)
                const int cv = col - 1280, kv = cv >> 6, d = cv & 63;
                unsigned short u[4];
                #pragma unroll
                for (int r = 0; r < 4; ++r) u[r] = f2bf(acc[mf][nf][r]);
                char* vrow = (char*)Vtw +
                    ((((size_t)b * KV_ + kv) * 64 + d) * (size_t)T_ * 2);
                *(u16x4*)(vrow + ((2 * t0) ^ ((d & 7) << 4))) = *(u16x4*)u;
            }
        }
    }
}

// ---------------------------------------------------------------------------
// Kernel 2: causal GQA flash attention, transposed-S form (mfma(K,Q) -> S^T),
// exp2-domain softmax (Q pre-scaled), defer-max.
// Single-buffered K/V (24 KB LDS -> 4+ blocks/CU), grid = one q-tile/block
// (1024 blocks, all resident: 4 blocks/CU interleave the per-tile chains).
// ---------------------------------------------------------------------------
__global__ __launch_bounds__(256) void attn_kernel(
    const unsigned short* __restrict__ Qg, const unsigned short* __restrict__ Kg,
    const unsigned short* __restrict__ Vtg, const float* __restrict__ maskp,
    unsigned short* __restrict__ attn_out)
{
    __shared__ __align__(16) unsigned char Kl[8192];      // [key][d], swizzled
    __shared__ __align__(16) unsigned char Vl[8192];      // [d][key], swizzled
    __shared__ __align__(16) unsigned char Pl[4][2048];   // per-wave P^T [q][key]

    const int tid  = threadIdx.x;
    const int lane = tid & 63;
    const int w    = tid >> 6;
    const int lr   = lane & 15;
    const int lg   = lane >> 4;

    const int bi = blockIdx.x;
    const int qt = 31 - (bi & 31);         // descending: long blocks first
    const int bh = bi >> 5;
    const int h  = bh & 15;
    const int b  = bh >> 4;
    const int kvh = h >> 2;
    const int q0 = qt * 64;
    const int qrow = q0 + w * 16 + lr;     // this lane's q row

    const char* Kb = (const char*)(Kg  + ((size_t)b * KV_ + kvh) * T_ * HD_);
    const char* Vb = (const char*)(Vtg + ((size_t)b * KV_ + kvh) * HD_ * T_);
    const float* mrow = maskp + b * T_;

    const int sr  = lane >> 3;          // staging row within 8-row block
    const int scb = (lane & 7) * 16;    // staging byte col
    unsigned char* Pw = &Pl[w][0];

    // Q fragments (B-operand: col=lane&15=q, k=d); pre-scaled in global
    const unsigned short* Qbase =
        Qg + (((size_t)b * H_ + h) * T_ + qrow) * HD_;
    const bf16x8 qf0 = *(const bf16x8*)(Qbase + lg * 8);
    const bf16x8 qf1 = *(const bf16x8*)(Qbase + 32 + lg * 8);

    f32x4 o[4] = {};
    float m = -1e30f, l = 0.f;

    for (int kt = 0; kt <= qt; ++kt) {
        const int k0 = kt * 64;

        // stage K/V tile (single buffer)
        #pragma unroll
        for (int i = 0; i < 2; ++i) {
            const int rb  = w * 2 + i;
            const int row = rb * 8 + sr;
            gload16(Kb + (size_t)(k0 + row) * 128 + scb, &Kl[rb * 1024]);
            gload16(Vb + (size_t)row * 4096 + 2 * k0 + scb, &Vl[rb * 1024]);
        }
        __syncthreads();   // staging landed (vmcnt drained before barrier)

        // mask values for this lane's 16 keys (float4 per n)
        f32x4 mv[4];
        #pragma unroll
        for (int n = 0; n < 4; ++n)
            mv[n] = *(const f32x4*)&mrow[k0 + 16 * n + 4 * lg];

        // QK^T transposed: s[n][r] = S[key=k0+16n+4lg+r][q=qrow] (exp2-dom)
        f32x4 s[4] = {};
        __builtin_amdgcn_s_setprio(1);
        #pragma unroll
        for (int n = 0; n < 4; ++n) {
            const int key = 16 * n + lr;
            #pragma unroll
            for (int ks = 0; ks < 2; ++ks) {
                bf16x8 kb = *(const bf16x8*)(Kl +
                    ((key * 128 + 64 * ks + lg * 16) ^ ((key & 7) << 4)));
                s[n] = __builtin_amdgcn_mfma_f32_16x16x32_bf16(
                    kb, ks == 0 ? qf0 : qf1, s[n], 0, 0, 0);
            }
        }
        __builtin_amdgcn_s_setprio(0);

        // mask (+ causal on diagonal tile); no scale mul (folded into Q)
        if (kt == qt) {
            #pragma unroll
            for (int n = 0; n < 4; ++n)
                #pragma unroll
                for (int r = 0; r < 4; ++r) {
                    const int keyg = k0 + 16 * n + 4 * lg + r;
                    bool ok = (keyg <= qrow) && (mv[n][r] > 0.f);
                    s[n][r] = ok ? s[n][r] : -1e30f;
                }
        } else {
            #pragma unroll
            for (int n = 0; n < 4; ++n)
                #pragma unroll
                for (int r = 0; r < 4; ++r)
                    s[n][r] = (mv[n][r] > 0.f) ? s[n][r] : -1e30f;
        }

        // online softmax, exp2-domain, defer-max (THR=8)
        float mx = s[0][0];
        #pragma unroll
        for (int n = 0; n < 4; ++n)
            #pragma unroll
            for (int r = 0; r < 4; ++r)
                if (n || r) mx = fmaxf(mx, s[n][r]);
        mx = fmaxf(mx, __shfl_xor(mx, 16));
        mx = fmaxf(mx, __shfl_xor(mx, 32));
        if (!__all(mx <= m + 8.f)) {          // wave-uniform rescale
            const float mnew = fmaxf(m, mx);
            const float alpha = exp2f(m - mnew);
            m = mnew;
            l *= alpha;
            #pragma unroll
            for (int n = 0; n < 4; ++n) o[n] *= alpha;
        }
        float rsum = 0.f;
        #pragma unroll
        for (int n = 0; n < 4; ++n)
            #pragma unroll
            for (int r = 0; r < 4; ++r) {
                float pv = exp2f(s[n][r] - m);
                s[n][r] = pv;
                rsum += pv;
            }
        rsum += __shfl_xor(rsum, 16);
        rsum += __shfl_xor(rsum, 32);
        l += rsum;

        // P^T -> wave-private LDS: row q=lr, 4 consecutive keys per 8B
        #pragma unroll
        for (int n = 0; n < 4; ++n) {
            unsigned int w0 = (unsigned int)f2bf(s[n][0]) |
                              ((unsigned int)f2bf(s[n][1]) << 16);
            unsigned int w1 = (unsigned int)f2bf(s[n][2]) |
                              ((unsigned int)f2bf(s[n][3]) << 16);
            uint2 wv; wv.x = w0; wv.y = w1;
            *(uint2*)(Pw + ((lr * 128 + 32 * n + 8 * lg) ^ ((lr & 7) << 4))) = wv;
        }
        bf16x8 pa0 = *(const bf16x8*)(Pw + ((lr * 128 +      lg * 16) ^ ((lr & 7) << 4)));
        bf16x8 pa1 = *(const bf16x8*)(Pw + ((lr * 128 + 64 + lg * 16) ^ ((lr & 7) << 4)));

        // PV transposed: o[n][r] = O[q=qrow][d=16n+4lg+r]
        __builtin_amdgcn_s_setprio(1);
        #pragma unroll
        for (int n = 0; n < 4; ++n) {
            const int d = 16 * n + lr;
            #pragma unroll
            for (int ks = 0; ks < 2; ++ks) {
                bf16x8 vb = *(const bf16x8*)(Vl +
                    ((d * 128 + 64 * ks + lg * 16) ^ ((d & 7) << 4)));
                o[n] = __builtin_amdgcn_mfma_f32_16x16x32_bf16(
                    vb, ks == 0 ? pa0 : pa1, o[n], 0, 0, 0);
            }
        }
        __builtin_amdgcn_s_setprio(0);

        __syncthreads();   // all reads done before next tile's staging
    }

    // epilogue: lane owns q=qrow, d = 16n+4lg+{0..3}
    const float linv = 1.f / l;
    unsigned short* orow = attn_out + ((size_t)b * T_ + qrow) * DIM_ + h * HD_;
    #pragma unroll
    for (int n = 0; n < 4; ++n) {
        unsigned short u[4];
        #pragma unroll
        for (int r = 0; r < 4; ++r) u[r] = f2bf(o[n][r] * linv);
        *(u16x4*)&orow[16 * n + 4 * lg] = *(u16x4*)u;
    }
}

// ---------------------------------------------------------------------------
// Kernel 3: output projection bf16 MFMA. d_out = attnb @ Wot^T (f32 out)
// ---------------------------------------------------------------------------
__global__ __launch_bounds__(256) void outproj_mfma_kernel(
    const unsigned short* __restrict__ Ab, const unsigned short* __restrict__ Wot,
    float* __restrict__ out)
{
    __shared__ __align__(16) unsigned char As[16384];
    __shared__ __align__(16) unsigned char Bs[16384];

    const int tid = threadIdx.x, lane = tid & 63, w = tid >> 6;
    const int lr = lane & 15, lg = lane >> 4;
    const int wm = w >> 1, wn = w & 1;
    const int bn = blockIdx.x, bm = blockIdx.y;
    const int m0 = bm * 128, n0 = bn * 128;

    const int chunkR = lane >> 3;
    const int srcOff = 8 * ((lane & 7) ^ chunkR);

    f32x4 acc[4][4] = {};

    for (int k0 = 0; k0 < 1024; k0 += 64) {
        __syncthreads();
        #pragma unroll
        for (int i = 0; i < 4; ++i) {
            const int chunk = w * 4 + i;
            const int row = chunk * 8 + chunkR;
            gload16(Ab  + (size_t)(m0 + row) * 1024 + k0 + srcOff, As + chunk * 1024);
            gload16(Wot + (size_t)(n0 + row) * 1024 + k0 + srcOff, Bs + chunk * 1024);
        }
        __syncthreads();
        #pragma unroll
        for (int kk = 0; kk < 2; ++kk) {
            bf16x8 af[4], bfr[4];
            #pragma unroll
            for (int mf = 0; mf < 4; ++mf) {
                const int row = wm * 64 + mf * 16 + lr;
                af[mf] = *(const bf16x8*)(As + row * 128 +
                          ((kk * 64 + lg * 16) ^ ((row & 7) << 4)));
            }
            #pragma unroll
            for (int nf = 0; nf < 4; ++nf) {
                const int row = wn * 64 + nf * 16 + lr;
                bfr[nf] = *(const bf16x8*)(Bs + row * 128 +
                          ((kk * 64 + lg * 16) ^ ((row & 7) << 4)));
            }
            #pragma unroll
            for (int mf = 0; mf < 4; ++mf)
                #pragma unroll
                for (int nf = 0; nf < 4; ++nf)
                    acc[mf][nf] = __builtin_amdgcn_mfma_f32_16x16x32_bf16(
                        af[mf], bfr[nf], acc[mf][nf], 0, 0, 0);
        }
    }

    #pragma unroll
    for (int nf = 0; nf < 4; ++nf) {
        const int col = n0 + wn * 64 + nf * 16 + lr;
        #pragma unroll
        for (int mf = 0; mf < 4; ++mf) {
            const int mrow = m0 + wm * 64 + mf * 16 + lg * 4;
            #pragma unroll
            for (int r = 0; r < 4; ++r)
                out[(size_t)(mrow + r) * 1024 + col] = acc[mf][nf][r];
        }
    }
}

// ---------------------------------------------------------------------------
extern "C" void kernel_launch(void* const* d_in, const int* in_sizes, int n_in,
                              void* d_out, int out_size, void* d_ws, size_t ws_size,
                              hipStream_t stream)
{
    const float* x     = (const float*)d_in[0];
    const float* sinp  = (const float*)d_in[1];
    const float* cosp  = (const float*)d_in[2];
    const float* maskp = (const float*)d_in[3];
    const float* Wq    = (const float*)d_in[4];
    const float* Wk    = (const float*)d_in[5];
    const float* Wv    = (const float*)d_in[6];
    const float* Wo    = (const float*)d_in[7];

    unsigned short* wsb = (unsigned short*)d_ws;
    unsigned short* xb  = wsb + XB_OFF;
    unsigned short* Wt  = wsb + WT_OFF;
    unsigned short* Wot = wsb + WOT_OFF;
    unsigned short* Qw  = wsb + QB_OFF;
    unsigned short* Kw  = wsb + KB_OFF;
    unsigned short* Vtw = wsb + VTB_OFF;
    unsigned short* Ab  = wsb + AB_OFF;
    float* out = (float*)d_out;

    cvt_kernel<<<2048, 256, 0, stream>>>(x, xb);
    wtrans_kernel<<<dim3(16, 16), 256, 0, stream>>>(Wq, Wt, 1024);
    wtrans_kernel<<<dim3(4, 16), 256, 0, stream>>>(Wk, Wt + 1024u * 1024u, 256);
    wtrans_kernel<<<dim3(4, 16), 256, 0, stream>>>(Wv, Wt + 1280u * 1024u, 256);
    wtrans_kernel<<<dim3(16, 16), 256, 0, stream>>>(Wo, Wot, 1024);

    qkv_mfma_kernel<<<dim3(12, 32), 256, 0, stream>>>(xb, Wt, sinp, cosp,
                                                      Qw, Kw, Vtw);
    attn_kernel<<<dim3(B_ * H_ * 32), 256, 0, stream>>>(
        Qw, Kw, Vtw, maskp, Ab);
    outproj_mfma_kernel<<<dim3(8, 32), 256, 0, stream>>>(Ab, Wot, out);
}

// Round 9
// 156.009 us; speedup vs baseline: 1.0839x; 1.0839x over previous
//
#include <hip/hip_runtime.h>
#include <math.h>

typedef __attribute__((ext_vector_type(8))) short bf16x8;
typedef __attribute__((ext_vector_type(4))) float f32x4;
typedef __attribute__((ext_vector_type(4))) unsigned short u16x4;

#define B_    2
#define T_    2048
#define DIM_  1024
#define H_    16
#define KV_   4
#define HD_   64

// 1/sqrt(HD) * log2(e): folded into Q at projection time -> S is exp2-domain
#define QSCALE 0.1803368801111437f

static __device__ __forceinline__ unsigned short f2bf(float f) {
    union { float f; unsigned int u; } v; v.f = f;
    unsigned int r = v.u + 0x7fff + ((v.u >> 16) & 1);   // RNE
    return (unsigned short)(r >> 16);
}

static __device__ __forceinline__ void gload16(const void* g, void* l) {
    __builtin_amdgcn_global_load_lds(
        (const __attribute__((address_space(1))) unsigned int*)g,
        (__attribute__((address_space(3))) unsigned int*)l, 16, 0, 0);
}

// Workspace (unsigned short elements):
//   xb   bf16 [4096][1024]          off 0
//   Wt   bf16 [1536][1024]          off 4194304   (Wq^T | Wk^T | Wv^T rows)
//   Wot  bf16 [1024][1024]          off 5767168
//   Q    bf16 [B][H][T][64]         off 6815744   (row-major, PRE-SCALED by QSCALE)
//   K    bf16 [B][KV][T][64]        off 11010048  (XOR-swizzled rows: 2d ^ ((t&7)<<4))
//   Vt   bf16 [B][KV][64][T]        off 12058624  (XOR-swizzled: 2t ^ ((d&7)<<4))
//   attnb bf16 [B][T][DIM]          off 13107200
#define XB_OFF   0u
#define WT_OFF   4194304u
#define WOT_OFF  5767168u
#define QB_OFF   6815744u
#define KB_OFF   11010048u
#define VTB_OFF  12058624u
#define AB_OFF   13107200u

// ---------------------------------------------------------------------------
// Pre-pass: f32 -> bf16 convert (8 elems/thread)
// ---------------------------------------------------------------------------
__global__ __launch_bounds__(256) void cvt_kernel(
    const float* __restrict__ in, unsigned short* __restrict__ out)
{
    const size_t i = ((size_t)blockIdx.x * 256 + threadIdx.x) * 8;
    float4 a = *(const float4*)&in[i];
    float4 b = *(const float4*)&in[i + 4];
    unsigned short u[8] = {f2bf(a.x), f2bf(a.y), f2bf(a.z), f2bf(a.w),
                           f2bf(b.x), f2bf(b.y), f2bf(b.z), f2bf(b.w)};
    *(bf16x8*)&out[i] = *(bf16x8*)u;
}

// ---------------------------------------------------------------------------
// Pre-pass: W f32 [1024][N] -> Wt bf16 [N][1024]  (64x64 LDS tile transpose)
// ---------------------------------------------------------------------------
__global__ __launch_bounds__(256) void wtrans_kernel(
    const float* __restrict__ W, unsigned short* __restrict__ Wt, int N)
{
    __shared__ float Ts[64][65];
    const int n0 = blockIdx.x * 64, k0 = blockIdx.y * 64;
    const int tid = threadIdx.x;
    const int r = tid >> 4, c4 = (tid & 15) * 4;
    #pragma unroll
    for (int i = 0; i < 4; ++i) {
        float4 v = *(const float4*)&W[(size_t)(k0 + r + 16 * i) * N + n0 + c4];
        Ts[r + 16 * i][c4 + 0] = v.x; Ts[r + 16 * i][c4 + 1] = v.y;
        Ts[r + 16 * i][c4 + 2] = v.z; Ts[r + 16 * i][c4 + 3] = v.w;
    }
    __syncthreads();
    const int rn = tid >> 3, ck = (tid & 7) * 8;
    #pragma unroll
    for (int i = 0; i < 2; ++i) {
        int n = rn + 32 * i;
        unsigned short u[8];
        #pragma unroll
        for (int e = 0; e < 8; ++e) u[e] = f2bf(Ts[ck + e][n]);
        *(bf16x8*)&Wt[(size_t)(n0 + n) * 1024 + k0 + ck] = *(bf16x8*)u;
    }
}

// ---------------------------------------------------------------------------
// Kernel 1: QKV bf16 MFMA GEMM + RoPE epilogue.
// C[4096][1536] = xb @ Wt^T. 128x128 tile, BK=64, 4 waves of 64x64.
// Q stores pre-scaled by QSCALE; K and Vt stored XOR-swizzled for attention's
// linear global_load_lds staging.
// ---------------------------------------------------------------------------
__global__ __launch_bounds__(256) void qkv_mfma_kernel(
    const unsigned short* __restrict__ xb, const unsigned short* __restrict__ Wt,
    const float* __restrict__ sinp, const float* __restrict__ cosp,
    unsigned short* __restrict__ Qw, unsigned short* __restrict__ Kw,
    unsigned short* __restrict__ Vtw)
{
    __shared__ __align__(16) unsigned char As[16384];   // [128 m][128B], XOR-swizzled
    __shared__ __align__(16) unsigned char Bs[16384];   // [128 n][128B]

    const int tid = threadIdx.x, lane = tid & 63, w = tid >> 6;
    const int lr = lane & 15, lg = lane >> 4;
    const int wm = w >> 1, wn = w & 1;
    const int bn = blockIdx.x, bm = blockIdx.y;
    const int m0 = bm * 128, n0 = bn * 128;

    const int chunkR = lane >> 3;                    // row within 8-row chunk
    const int srcOff = 8 * ((lane & 7) ^ chunkR);    // inverse-swizzled src (elems)

    f32x4 acc[4][4] = {};

    for (int k0 = 0; k0 < 1024; k0 += 64) {
        __syncthreads();
        #pragma unroll
        for (int i = 0; i < 4; ++i) {
            const int chunk = w * 4 + i;
            const int row = chunk * 8 + chunkR;
            gload16(xb + (size_t)(m0 + row) * 1024 + k0 + srcOff, As + chunk * 1024);
            gload16(Wt + (size_t)(n0 + row) * 1024 + k0 + srcOff, Bs + chunk * 1024);
        }
        __syncthreads();   // compiler drains vmcnt before s_barrier
        #pragma unroll
        for (int kk = 0; kk < 2; ++kk) {
            bf16x8 af[4], bfr[4];
            #pragma unroll
            for (int mf = 0; mf < 4; ++mf) {
                const int row = wm * 64 + mf * 16 + lr;
                af[mf] = *(const bf16x8*)(As + row * 128 +
                          ((kk * 64 + lg * 16) ^ ((row & 7) << 4)));
            }
            #pragma unroll
            for (int nf = 0; nf < 4; ++nf) {
                const int row = wn * 64 + nf * 16 + lr;
                bfr[nf] = *(const bf16x8*)(Bs + row * 128 +
                          ((kk * 64 + lg * 16) ^ ((row & 7) << 4)));
            }
            #pragma unroll
            for (int mf = 0; mf < 4; ++mf)
                #pragma unroll
                for (int nf = 0; nf < 4; ++nf)
                    acc[mf][nf] = __builtin_amdgcn_mfma_f32_16x16x32_bf16(
                        af[mf], bfr[nf], acc[mf][nf], 0, 0, 0);
        }
    }

    // Epilogue: C row m = m0+wm*64+mf*16+lg*4+r, col = n0+wn*64+nf*16+lr
    const float rsign = (lane & 1) ? 1.f : -1.f;
    #pragma unroll
    for (int nf = 0; nf < 4; ++nf) {
        const int col = n0 + wn * 64 + nf * 16 + lr;
        #pragma unroll
        for (int mf = 0; mf < 4; ++mf) {
            const int mrow = m0 + wm * 64 + mf * 16 + lg * 4;
            const int b = mrow >> 11;
            const int t0 = mrow & 2047;
            if (col < 1280) {   // Q or K: RoPE (block-uniform branch)
                const int d = col & 63;
                #pragma unroll
                for (int r = 0; r < 4; ++r) {
                    float val = acc[mf][nf][r];
                    float partner = __shfl_xor(val, 1);
                    const int t = t0 + r;
                    float cs = cosp[t * 64 + d], sn = sinp[t * 64 + d];
                    float rv = val * cs + rsign * partner * sn;
                    if (col < 1024) {
                        const int h = col >> 6;
                        Qw[(((size_t)b * H_ + h) * T_ + t) * 64 + d] =
                            f2bf(rv * QSCALE);
                    } else {
                        const int kv = (col - 1024) >> 6;
                        // swizzled store: byte = t*128 + (2d ^ ((t&7)<<4))
                        char* krow = (char*)Kw +
                            ((((size_t)b * KV_ + kv) * T_ + t) << 7);
                        *(unsigned short*)(krow + ((2 * d) ^ ((t & 7) << 4))) =
                            f2bf(rv);
                    }
                }
            } else {            // V: transposed swizzled store, 4 t packed (8B)
                const int cv = col - 1280, kv = cv >> 6, d = cv & 63;
                unsigned short u[4];
                #pragma unroll
                for (int r = 0; r < 4; ++r) u[r] = f2bf(acc[mf][nf][r]);
                char* vrow = (char*)Vtw +
                    ((((size_t)b * KV_ + kv) * 64 + d) * (size_t)T_ * 2);
                *(u16x4*)(vrow + ((2 * t0) ^ ((d & 7) << 4))) = *(u16x4*)u;
            }
        }
    }
}

// ---------------------------------------------------------------------------
// Kernel 2: causal GQA flash attention, transposed-S form (mfma(K,Q) -> S^T),
// exp2-domain softmax (Q pre-scaled).
// Block = 128 threads = 2 waves x 16 q-rows = one 32-row q-subtile per pass;
// two paired passes (63-p, then p) -> uniform 33 key-tiles per block.
// Grid = B*H*32 = 1024 blocks; LDS 20KB -> target 4 waves/SIMD.
// ---------------------------------------------------------------------------
__global__ __launch_bounds__(128, 4) void attn_kernel(
    const unsigned short* __restrict__ Qg, const unsigned short* __restrict__ Kg,
    const unsigned short* __restrict__ Vtg, const float* __restrict__ maskp,
    unsigned short* __restrict__ attn_out)
{
    __shared__ __align__(16) unsigned char Kl[8192];      // [key][d], swizzled
    __shared__ __align__(16) unsigned char Vl[8192];      // [d][key], swizzled
    __shared__ __align__(16) unsigned char Pl[2][2048];   // per-wave P^T [q][key]

    const int tid  = threadIdx.x;
    const int lane = tid & 63;
    const int w    = tid >> 6;             // 0..1
    const int lr   = lane & 15;
    const int lg   = lane >> 4;

    const int bi = blockIdx.x;
    const int pairIdx = bi & 31;           // 0..31
    const int bh = bi >> 5;
    const int h  = bh & 15;
    const int b  = bh >> 4;
    const int kvh = h >> 2;

    const char* Kb = (const char*)(Kg  + ((size_t)b * KV_ + kvh) * T_ * HD_);
    const char* Vb = (const char*)(Vtg + ((size_t)b * KV_ + kvh) * HD_ * T_);
    const float* mrow = maskp + b * T_;

    const int sr  = lane >> 3;          // staging row within 8-row block
    const int scb = (lane & 7) * 16;    // staging byte col
    unsigned char* Pw = &Pl[w][0];

    for (int pass = 0; pass < 2; ++pass) {
        const int qs = pass ? pairIdx : 63 - pairIdx;   // 32-row subtile index
        const int q0 = qs * 32;
        const int qrow = q0 + w * 16 + lr;              // this lane's q row
        const int nt = (qs >> 1) + 1;                   // key-tiles (64 keys)

        // Q fragments (B-operand: col=lane&15=q, k=d); pre-scaled in global
        const unsigned short* Qbase =
            Qg + (((size_t)b * H_ + h) * T_ + qrow) * HD_;
        const bf16x8 qf0 = *(const bf16x8*)(Qbase + lg * 8);
        const bf16x8 qf1 = *(const bf16x8*)(Qbase + 32 + lg * 8);

        f32x4 o[4] = {};
        float m = -1e30f, l = 0.f;

        for (int kt = 0; kt < nt; ++kt) {
            const int k0 = kt * 64;

            // stage K/V tile (single buffer): 2 waves x 4 row-blocks each
            #pragma unroll
            for (int i = 0; i < 4; ++i) {
                const int rb  = w * 4 + i;
                const int row = rb * 8 + sr;
                gload16(Kb + (size_t)(k0 + row) * 128 + scb, &Kl[rb * 1024]);
                gload16(Vb + (size_t)row * 4096 + 2 * k0 + scb, &Vl[rb * 1024]);
            }
            __syncthreads();   // staging landed (vmcnt drained before barrier)

            // mask values for this lane's 16 keys (float4 per n)
            f32x4 mv[4];
            #pragma unroll
            for (int n = 0; n < 4; ++n)
                mv[n] = *(const f32x4*)&mrow[k0 + 16 * n + 4 * lg];

            // QK^T transposed: s[n][r] = S[key=k0+16n+4lg+r][q=qrow] (exp2-dom)
            f32x4 s[4] = {};
            __builtin_amdgcn_s_setprio(1);
            #pragma unroll
            for (int n = 0; n < 4; ++n) {
                const int key = 16 * n + lr;
                #pragma unroll
                for (int ks = 0; ks < 2; ++ks) {
                    bf16x8 kb = *(const bf16x8*)(Kl +
                        ((key * 128 + 64 * ks + lg * 16) ^ ((key & 7) << 4)));
                    s[n] = __builtin_amdgcn_mfma_f32_16x16x32_bf16(
                        kb, ks == 0 ? qf0 : qf1, s[n], 0, 0, 0);
                }
            }
            __builtin_amdgcn_s_setprio(0);

            // mask (+ causal on diagonal tile); no scale mul (folded into Q)
            if (kt == nt - 1) {
                #pragma unroll
                for (int n = 0; n < 4; ++n)
                    #pragma unroll
                    for (int r = 0; r < 4; ++r) {
                        const int keyg = k0 + 16 * n + 4 * lg + r;
                        bool ok = (keyg <= qrow) && (mv[n][r] > 0.f);
                        s[n][r] = ok ? s[n][r] : -1e30f;
                    }
            } else {
                #pragma unroll
                for (int n = 0; n < 4; ++n)
                    #pragma unroll
                    for (int r = 0; r < 4; ++r)
                        s[n][r] = (mv[n][r] > 0.f) ? s[n][r] : -1e30f;
            }

            // online softmax, exp2-domain (unconditional rescale, R5 form)
            float mx = s[0][0];
            #pragma unroll
            for (int n = 0; n < 4; ++n)
                #pragma unroll
                for (int r = 0; r < 4; ++r)
                    if (n || r) mx = fmaxf(mx, s[n][r]);
            mx = fmaxf(mx, __shfl_xor(mx, 16));
            mx = fmaxf(mx, __shfl_xor(mx, 32));
            const float mnew = fmaxf(m, mx);
            const float alpha = exp2f(m - mnew);
            m = mnew;
            float rsum = 0.f;
            #pragma unroll
            for (int n = 0; n < 4; ++n)
                #pragma unroll
                for (int r = 0; r < 4; ++r) {
                    float pv = exp2f(s[n][r] - mnew);
                    s[n][r] = pv;
                    rsum += pv;
                }
            rsum += __shfl_xor(rsum, 16);
            rsum += __shfl_xor(rsum, 32);
            l = l * alpha + rsum;
            #pragma unroll
            for (int n = 0; n < 4; ++n) o[n] *= alpha;

            // P^T -> wave-private LDS: row q=lr, 4 consecutive keys per 8B
            #pragma unroll
            for (int n = 0; n < 4; ++n) {
                unsigned int w0 = (unsigned int)f2bf(s[n][0]) |
                                  ((unsigned int)f2bf(s[n][1]) << 16);
                unsigned int w1 = (unsigned int)f2bf(s[n][2]) |
                                  ((unsigned int)f2bf(s[n][3]) << 16);
                uint2 wv; wv.x = w0; wv.y = w1;
                *(uint2*)(Pw + ((lr * 128 + 32 * n + 8 * lg) ^ ((lr & 7) << 4))) = wv;
            }
            bf16x8 pa0 = *(const bf16x8*)(Pw + ((lr * 128 +      lg * 16) ^ ((lr & 7) << 4)));
            bf16x8 pa1 = *(const bf16x8*)(Pw + ((lr * 128 + 64 + lg * 16) ^ ((lr & 7) << 4)));

            // PV transposed: o[n][r] = O[q=qrow][d=16n+4lg+r]
            __builtin_amdgcn_s_setprio(1);
            #pragma unroll
            for (int n = 0; n < 4; ++n) {
                const int d = 16 * n + lr;
                #pragma unroll
                for (int ks = 0; ks < 2; ++ks) {
                    bf16x8 vb = *(const bf16x8*)(Vl +
                        ((d * 128 + 64 * ks + lg * 16) ^ ((d & 7) << 4)));
                    o[n] = __builtin_amdgcn_mfma_f32_16x16x32_bf16(
                        vb, ks == 0 ? pa0 : pa1, o[n], 0, 0, 0);
                }
            }
            __builtin_amdgcn_s_setprio(0);

            __syncthreads();   // all reads done before next tile's staging
        }

        // epilogue: lane owns q=qrow, d = 16n+4lg+{0..3}
        const float linv = 1.f / l;
        unsigned short* orow = attn_out + ((size_t)b * T_ + qrow) * DIM_ + h * HD_;
        #pragma unroll
        for (int n = 0; n < 4; ++n) {
            unsigned short u[4];
            #pragma unroll
            for (int r = 0; r < 4; ++r) u[r] = f2bf(o[n][r] * linv);
            *(u16x4*)&orow[16 * n + 4 * lg] = *(u16x4*)u;
        }
    }
}

// ---------------------------------------------------------------------------
// Kernel 3: output projection bf16 MFMA. d_out = attnb @ Wot^T (f32 out)
// ---------------------------------------------------------------------------
__global__ __launch_bounds__(256) void outproj_mfma_kernel(
    const unsigned short* __restrict__ Ab, const unsigned short* __restrict__ Wot,
    float* __restrict__ out)
{
    __shared__ __align__(16) unsigned char As[16384];
    __shared__ __align__(16) unsigned char Bs[16384];

    const int tid = threadIdx.x, lane = tid & 63, w = tid >> 6;
    const int lr = lane & 15, lg = lane >> 4;
    const int wm = w >> 1, wn = w & 1;
    const int bn = blockIdx.x, bm = blockIdx.y;
    const int m0 = bm * 128, n0 = bn * 128;

    const int chunkR = lane >> 3;
    const int srcOff = 8 * ((lane & 7) ^ chunkR);

    f32x4 acc[4][4] = {};

    for (int k0 = 0; k0 < 1024; k0 += 64) {
        __syncthreads();
        #pragma unroll
        for (int i = 0; i < 4; ++i) {
            const int chunk = w * 4 + i;
            const int row = chunk * 8 + chunkR;
            gload16(Ab  + (size_t)(m0 + row) * 1024 + k0 + srcOff, As + chunk * 1024);
            gload16(Wot + (size_t)(n0 + row) * 1024 + k0 + srcOff, Bs + chunk * 1024);
        }
        __syncthreads();
        #pragma unroll
        for (int kk = 0; kk < 2; ++kk) {
            bf16x8 af[4], bfr[4];
            #pragma unroll
            for (int mf = 0; mf < 4; ++mf) {
                const int row = wm * 64 + mf * 16 + lr;
                af[mf] = *(const bf16x8*)(As + row * 128 +
                          ((kk * 64 + lg * 16) ^ ((row & 7) << 4)));
            }
            #pragma unroll
            for (int nf = 0; nf < 4; ++nf) {
                const int row = wn * 64 + nf * 16 + lr;
                bfr[nf] = *(const bf16x8*)(Bs + row * 128 +
                          ((kk * 64 + lg * 16) ^ ((row & 7) << 4)));
            }
            #pragma unroll
            for (int mf = 0; mf < 4; ++mf)
                #pragma unroll
                for (int nf = 0; nf < 4; ++nf)
                    acc[mf][nf] = __builtin_amdgcn_mfma_f32_16x16x32_bf16(
                        af[mf], bfr[nf], acc[mf][nf], 0, 0, 0);
        }
    }

    #pragma unroll
    for (int nf = 0; nf < 4; ++nf) {
        const int col = n0 + wn * 64 + nf * 16 + lr;
        #pragma unroll
        for (int mf = 0; mf < 4; ++mf) {
            const int mrow = m0 + wm * 64 + mf * 16 + lg * 4;
            #pragma unroll
            for (int r = 0; r < 4; ++r)
                out[(size_t)(mrow + r) * 1024 + col] = acc[mf][nf][r];
        }
    }
}

// ---------------------------------------------------------------------------
extern "C" void kernel_launch(void* const* d_in, const int* in_sizes, int n_in,
                              void* d_out, int out_size, void* d_ws, size_t ws_size,
                              hipStream_t stream)
{
    const float* x     = (const float*)d_in[0];
    const float* sinp  = (const float*)d_in[1];
    const float* cosp  = (const float*)d_in[2];
    const float* maskp = (const float*)d_in[3];
    const float* Wq    = (const float*)d_in[4];
    const float* Wk    = (const float*)d_in[5];
    const float* Wv    = (const float*)d_in[6];
    const float* Wo    = (const float*)d_in[7];

    unsigned short* wsb = (unsigned short*)d_ws;
    unsigned short* xb  = wsb + XB_OFF;
    unsigned short* Wt  = wsb + WT_OFF;
    unsigned short* Wot = wsb + WOT_OFF;
    unsigned short* Qw  = wsb + QB_OFF;
    unsigned short* Kw  = wsb + KB_OFF;
    unsigned short* Vtw = wsb + VTB_OFF;
    unsigned short* Ab  = wsb + AB_OFF;
    float* out = (float*)d_out;

    cvt_kernel<<<2048, 256, 0, stream>>>(x, xb);
    wtrans_kernel<<<dim3(16, 16), 256, 0, stream>>>(Wq, Wt, 1024);
    wtrans_kernel<<<dim3(4, 16), 256, 0, stream>>>(Wk, Wt + 1024u * 1024u, 256);
    wtrans_kernel<<<dim3(4, 16), 256, 0, stream>>>(Wv, Wt + 1280u * 1024u, 256);
    wtrans_kernel<<<dim3(16, 16), 256, 0, stream>>>(Wo, Wot, 1024);

    qkv_mfma_kernel<<<dim3(12, 32), 256, 0, stream>>>(xb, Wt, sinp, cosp,
                                                      Qw, Kw, Vtw);
    attn_kernel<<<dim3(B_ * H_ * 32), 128, 0, stream>>>(
        Qw, Kw, Vtw, maskp, Ab);
    outproj_mfma_kernel<<<dim3(8, 32), 256, 0, stream>>>(Ab, Wot, out);
}

// Round 10
// 137.558 us; speedup vs baseline: 1.2292x; 1.1341x over previous
//
#include <hip/hip_runtime.h>
#include <math.h>

typedef __attribute__((ext_vector_type(8))) short bf16x8;
typedef __attribute__((ext_vector_type(4))) float f32x4;
typedef __attribute__((ext_vector_type(4))) unsigned short u16x4;

#define B_    2
#define T_    2048
#define DIM_  1024
#define H_    16
#define KV_   4
#define HD_   64

// 1/sqrt(HD) * log2(e): folded into Q at projection time -> S is exp2-domain
#define QSCALE 0.1803368801111437f

static __device__ __forceinline__ unsigned short f2bf(float f) {
    union { float f; unsigned int u; } v; v.f = f;
    unsigned int r = v.u + 0x7fff + ((v.u >> 16) & 1);   // RNE
    return (unsigned short)(r >> 16);
}

static __device__ __forceinline__ void gload16(const void* g, void* l) {
    __builtin_amdgcn_global_load_lds(
        (const __attribute__((address_space(1))) unsigned int*)g,
        (__attribute__((address_space(3))) unsigned int*)l, 16, 0, 0);
}

// Workspace (unsigned short elements):
//   xb   bf16 [4096][1024]          off 0
//   Wt   bf16 [1536][1024]          off 4194304   (Wq^T | Wk^T | Wv^T rows)
//   Wot  bf16 [1024][1024]          off 5767168
//   Q    bf16 [B][H][T][64]         off 6815744   (row-major, PRE-SCALED by QSCALE)
//   K    bf16 [B][KV][T][64]        off 11010048  (XOR-swizzled rows: 2d ^ ((t&7)<<4))
//   Vt   bf16 [B][KV][64][T]        off 12058624  (XOR-swizzled: 2t ^ ((d&7)<<4))
//   attnb bf16 [B][T][DIM]          off 13107200
#define XB_OFF   0u
#define WT_OFF   4194304u
#define WOT_OFF  5767168u
#define QB_OFF   6815744u
#define KB_OFF   11010048u
#define VTB_OFF  12058624u
#define AB_OFF   13107200u

// ---------------------------------------------------------------------------
// Pre-pass: f32 -> bf16 convert (8 elems/thread)
// ---------------------------------------------------------------------------
__global__ __launch_bounds__(256) void cvt_kernel(
    const float* __restrict__ in, unsigned short* __restrict__ out)
{
    const size_t i = ((size_t)blockIdx.x * 256 + threadIdx.x) * 8;
    float4 a = *(const float4*)&in[i];
    float4 b = *(const float4*)&in[i + 4];
    unsigned short u[8] = {f2bf(a.x), f2bf(a.y), f2bf(a.z), f2bf(a.w),
                           f2bf(b.x), f2bf(b.y), f2bf(b.z), f2bf(b.w)};
    *(bf16x8*)&out[i] = *(bf16x8*)u;
}

// ---------------------------------------------------------------------------
// Pre-pass: W f32 [1024][N] -> Wt bf16 [N][1024]  (64x64 LDS tile transpose)
// ---------------------------------------------------------------------------
__global__ __launch_bounds__(256) void wtrans_kernel(
    const float* __restrict__ W, unsigned short* __restrict__ Wt, int N)
{
    __shared__ float Ts[64][65];
    const int n0 = blockIdx.x * 64, k0 = blockIdx.y * 64;
    const int tid = threadIdx.x;
    const int r = tid >> 4, c4 = (tid & 15) * 4;
    #pragma unroll
    for (int i = 0; i < 4; ++i) {
        float4 v = *(const float4*)&W[(size_t)(k0 + r + 16 * i) * N + n0 + c4];
        Ts[r + 16 * i][c4 + 0] = v.x; Ts[r + 16 * i][c4 + 1] = v.y;
        Ts[r + 16 * i][c4 + 2] = v.z; Ts[r + 16 * i][c4 + 3] = v.w;
    }
    __syncthreads();
    const int rn = tid >> 3, ck = (tid & 7) * 8;
    #pragma unroll
    for (int i = 0; i < 2; ++i) {
        int n = rn + 32 * i;
        unsigned short u[8];
        #pragma unroll
        for (int e = 0; e < 8; ++e) u[e] = f2bf(Ts[ck + e][n]);
        *(bf16x8*)&Wt[(size_t)(n0 + n) * 1024 + k0 + ck] = *(bf16x8*)u;
    }
}

// ---------------------------------------------------------------------------
// Kernel 1: QKV bf16 MFMA GEMM + RoPE epilogue.
// C[4096][1536] = xb @ Wt^T. 128x128 tile, BK=64, 4 waves of 64x64.
// Q stores pre-scaled by QSCALE; K and Vt stored XOR-swizzled for attention's
// linear global_load_lds staging.
// ---------------------------------------------------------------------------
__global__ __launch_bounds__(256) void qkv_mfma_kernel(
    const unsigned short* __restrict__ xb, const unsigned short* __restrict__ Wt,
    const float* __restrict__ sinp, const float* __restrict__ cosp,
    unsigned short* __restrict__ Qw, unsigned short* __restrict__ Kw,
    unsigned short* __restrict__ Vtw)
{
    __shared__ __align__(16) unsigned char As[16384];   // [128 m][128B], XOR-swizzled
    __shared__ __align__(16) unsigned char Bs[16384];   // [128 n][128B]

    const int tid = threadIdx.x, lane = tid & 63, w = tid >> 6;
    const int lr = lane & 15, lg = lane >> 4;
    const int wm = w >> 1, wn = w & 1;
    const int bn = blockIdx.x, bm = blockIdx.y;
    const int m0 = bm * 128, n0 = bn * 128;

    const int chunkR = lane >> 3;                    // row within 8-row chunk
    const int srcOff = 8 * ((lane & 7) ^ chunkR);    // inverse-swizzled src (elems)

    f32x4 acc[4][4] = {};

    for (int k0 = 0; k0 < 1024; k0 += 64) {
        __syncthreads();
        #pragma unroll
        for (int i = 0; i < 4; ++i) {
            const int chunk = w * 4 + i;
            const int row = chunk * 8 + chunkR;
            gload16(xb + (size_t)(m0 + row) * 1024 + k0 + srcOff, As + chunk * 1024);
            gload16(Wt + (size_t)(n0 + row) * 1024 + k0 + srcOff, Bs + chunk * 1024);
        }
        __syncthreads();   // compiler drains vmcnt before s_barrier
        #pragma unroll
        for (int kk = 0; kk < 2; ++kk) {
            bf16x8 af[4], bfr[4];
            #pragma unroll
            for (int mf = 0; mf < 4; ++mf) {
                const int row = wm * 64 + mf * 16 + lr;
                af[mf] = *(const bf16x8*)(As + row * 128 +
                          ((kk * 64 + lg * 16) ^ ((row & 7) << 4)));
            }
            #pragma unroll
            for (int nf = 0; nf < 4; ++nf) {
                const int row = wn * 64 + nf * 16 + lr;
                bfr[nf] = *(const bf16x8*)(Bs + row * 128 +
                          ((kk * 64 + lg * 16) ^ ((row & 7) << 4)));
            }
            #pragma unroll
            for (int mf = 0; mf < 4; ++mf)
                #pragma unroll
                for (int nf = 0; nf < 4; ++nf)
                    acc[mf][nf] = __builtin_amdgcn_mfma_f32_16x16x32_bf16(
                        af[mf], bfr[nf], acc[mf][nf], 0, 0, 0);
        }
    }

    // Epilogue: C row m = m0+wm*64+mf*16+lg*4+r, col = n0+wn*64+nf*16+lr
    const float rsign = (lane & 1) ? 1.f : -1.f;
    #pragma unroll
    for (int nf = 0; nf < 4; ++nf) {
        const int col = n0 + wn * 64 + nf * 16 + lr;
        #pragma unroll
        for (int mf = 0; mf < 4; ++mf) {
            const int mrow = m0 + wm * 64 + mf * 16 + lg * 4;
            const int b = mrow >> 11;
            const int t0 = mrow & 2047;
            if (col < 1280) {   // Q or K: RoPE (block-uniform branch)
                const int d = col & 63;
                #pragma unroll
                for (int r = 0; r < 4; ++r) {
                    float val = acc[mf][nf][r];
                    float partner = __shfl_xor(val, 1);
                    const int t = t0 + r;
                    float cs = cosp[t * 64 + d], sn = sinp[t * 64 + d];
                    float rv = val * cs + rsign * partner * sn;
                    if (col < 1024) {
                        const int h = col >> 6;
                        Qw[(((size_t)b * H_ + h) * T_ + t) * 64 + d] =
                            f2bf(rv * QSCALE);
                    } else {
                        const int kv = (col - 1024) >> 6;
                        // swizzled store: byte = t*128 + (2d ^ ((t&7)<<4))
                        char* krow = (char*)Kw +
                            ((((size_t)b * KV_ + kv) * T_ + t) << 7);
                        *(unsigned short*)(krow + ((2 * d) ^ ((t & 7) << 4))) =
                            f2bf(rv);
                    }
                }
            } else {            // V: transposed swizzled store, 4 t packed (8B)
                const int cv = col - 1280, kv = cv >> 6, d = cv & 63;
                unsigned short u[4];
                #pragma unroll
                for (int r = 0; r < 4; ++r) u[r] = f2bf(acc[mf][nf][r]);
                char* vrow = (char*)Vtw +
                    ((((size_t)b * KV_ + kv) * 64 + d) * (size_t)T_ * 2);
                *(u16x4*)(vrow + ((2 * t0) ^ ((d & 7) << 4))) = *(u16x4*)u;
            }
        }
    }
}

// ---------------------------------------------------------------------------
// Kernel 2: causal GQA flash attention, transposed-S form (mfma(K,Q) -> S^T),
// exp2-domain softmax (Q pre-scaled).
// Block = 512 threads = 8 waves. Waves 0-3 process q-tile qtA=31-p, waves 4-7
// process q-tile qtB=p CONCURRENTLY, sharing one K/V staging loop over
// kt=0..qtA. Uniform useful work per block (132 wave-tiles). 512 blocks x
// 8 waves = 4096 waves = 16/CU (2 blocks/CU, LDS 32KB).
// Dispatch order pairs complementary-duration blocks at i and i+256.
// ---------------------------------------------------------------------------
__global__ __launch_bounds__(512, 4) void attn_kernel(
    const unsigned short* __restrict__ Qg, const unsigned short* __restrict__ Kg,
    const unsigned short* __restrict__ Vtg, const float* __restrict__ maskp,
    unsigned short* __restrict__ attn_out)
{
    __shared__ __align__(16) unsigned char Kl[8192];      // [key][d], swizzled
    __shared__ __align__(16) unsigned char Vl[8192];      // [d][key], swizzled
    __shared__ __align__(16) unsigned char Pl[8][2048];   // per-wave P^T [q][key]

    const int tid  = threadIdx.x;
    const int lane = tid & 63;
    const int w    = tid >> 6;             // 0..7
    const int grp  = w >> 2;               // 0 = long tile, 1 = short tile
    const int wq   = w & 3;                // wave-in-group
    const int lr   = lane & 15;
    const int lg   = lane >> 4;

    // dispatch mapping: blocks i and i+256 have complementary work (49 tiles)
    const int bi   = blockIdx.x;
    const int half = bi >> 8;
    const int j    = bi & 255;
    const int bh   = j >> 3;               // 0..31
    const int idx  = j & 7;
    const int p    = half ? (15 - idx) : idx;   // pair index 0..15
    const int qtA  = 31 - p;
    const int qt   = grp ? p : qtA;        // this wave's q-tile
    const int h    = bh & 15;
    const int b    = bh >> 4;
    const int kvh  = h >> 2;
    const int q0   = qt * 64;
    const int qrow = q0 + wq * 16 + lr;    // this lane's q row

    const char* Kb = (const char*)(Kg  + ((size_t)b * KV_ + kvh) * T_ * HD_);
    const char* Vb = (const char*)(Vtg + ((size_t)b * KV_ + kvh) * HD_ * T_);
    const float* mrow = maskp + b * T_;

    const int sr  = lane >> 3;          // staging row within 8-row block
    const int scb = (lane & 7) * 16;    // staging byte col
    unsigned char* Pw = &Pl[w][0];

    // Q fragments (B-operand: col=lane&15=q, k=d); pre-scaled in global
    const unsigned short* Qbase =
        Qg + (((size_t)b * H_ + h) * T_ + qrow) * HD_;
    const bf16x8 qf0 = *(const bf16x8*)(Qbase + lg * 8);
    const bf16x8 qf1 = *(const bf16x8*)(Qbase + 32 + lg * 8);

    f32x4 o[4] = {};
    float m = -1e30f, l = 0.f;

    for (int kt = 0; kt <= qtA; ++kt) {
        const int k0 = kt * 64;

        // stage K/V tile: 8 waves x (1 K row-block + 1 V row-block)
        {
            const int row = w * 8 + sr;
            gload16(Kb + (size_t)(k0 + row) * 128 + scb, &Kl[w * 1024]);
            gload16(Vb + (size_t)row * 4096 + 2 * k0 + scb, &Vl[w * 1024]);
        }
        __syncthreads();   // staging landed (vmcnt drained before barrier)

        if (kt <= qt) {    // wave-uniform: short-tile waves skip past their end
            // mask values for this lane's 16 keys (float4 per n)
            f32x4 mv[4];
            #pragma unroll
            for (int n = 0; n < 4; ++n)
                mv[n] = *(const f32x4*)&mrow[k0 + 16 * n + 4 * lg];

            // QK^T transposed: s[n][r] = S[key=k0+16n+4lg+r][q=qrow]
            f32x4 s[4] = {};
            __builtin_amdgcn_s_setprio(1);
            #pragma unroll
            for (int n = 0; n < 4; ++n) {
                const int key = 16 * n + lr;
                #pragma unroll
                for (int ks = 0; ks < 2; ++ks) {
                    bf16x8 kb = *(const bf16x8*)(Kl +
                        ((key * 128 + 64 * ks + lg * 16) ^ ((key & 7) << 4)));
                    s[n] = __builtin_amdgcn_mfma_f32_16x16x32_bf16(
                        kb, ks == 0 ? qf0 : qf1, s[n], 0, 0, 0);
                }
            }
            __builtin_amdgcn_s_setprio(0);

            // mask (+ causal on diagonal tile); no scale mul (folded into Q)
            if (kt == qt) {
                #pragma unroll
                for (int n = 0; n < 4; ++n)
                    #pragma unroll
                    for (int r = 0; r < 4; ++r) {
                        const int keyg = k0 + 16 * n + 4 * lg + r;
                        bool ok = (keyg <= qrow) && (mv[n][r] > 0.f);
                        s[n][r] = ok ? s[n][r] : -1e30f;
                    }
            } else {
                #pragma unroll
                for (int n = 0; n < 4; ++n)
                    #pragma unroll
                    for (int r = 0; r < 4; ++r)
                        s[n][r] = (mv[n][r] > 0.f) ? s[n][r] : -1e30f;
            }

            // online softmax, exp2-domain (unconditional rescale, R5 form)
            float mx = s[0][0];
            #pragma unroll
            for (int n = 0; n < 4; ++n)
                #pragma unroll
                for (int r = 0; r < 4; ++r)
                    if (n || r) mx = fmaxf(mx, s[n][r]);
            mx = fmaxf(mx, __shfl_xor(mx, 16));
            mx = fmaxf(mx, __shfl_xor(mx, 32));
            const float mnew = fmaxf(m, mx);
            const float alpha = exp2f(m - mnew);
            m = mnew;
            float rsum = 0.f;
            #pragma unroll
            for (int n = 0; n < 4; ++n)
                #pragma unroll
                for (int r = 0; r < 4; ++r) {
                    float pv = exp2f(s[n][r] - mnew);
                    s[n][r] = pv;
                    rsum += pv;
                }
            rsum += __shfl_xor(rsum, 16);
            rsum += __shfl_xor(rsum, 32);
            l = l * alpha + rsum;
            #pragma unroll
            for (int n = 0; n < 4; ++n) o[n] *= alpha;

            // P^T -> wave-private LDS: row q=lr, 4 consecutive keys per 8B
            #pragma unroll
            for (int n = 0; n < 4; ++n) {
                unsigned int w0 = (unsigned int)f2bf(s[n][0]) |
                                  ((unsigned int)f2bf(s[n][1]) << 16);
                unsigned int w1 = (unsigned int)f2bf(s[n][2]) |
                                  ((unsigned int)f2bf(s[n][3]) << 16);
                uint2 wv; wv.x = w0; wv.y = w1;
                *(uint2*)(Pw + ((lr * 128 + 32 * n + 8 * lg) ^ ((lr & 7) << 4))) = wv;
            }
            bf16x8 pa0 = *(const bf16x8*)(Pw + ((lr * 128 +      lg * 16) ^ ((lr & 7) << 4)));
            bf16x8 pa1 = *(const bf16x8*)(Pw + ((lr * 128 + 64 + lg * 16) ^ ((lr & 7) << 4)));

            // PV transposed: o[n][r] = O[q=qrow][d=16n+4lg+r]
            __builtin_amdgcn_s_setprio(1);
            #pragma unroll
            for (int n = 0; n < 4; ++n) {
                const int d = 16 * n + lr;
                #pragma unroll
                for (int ks = 0; ks < 2; ++ks) {
                    bf16x8 vb = *(const bf16x8*)(Vl +
                        ((d * 128 + 64 * ks + lg * 16) ^ ((d & 7) << 4)));
                    o[n] = __builtin_amdgcn_mfma_f32_16x16x32_bf16(
                        vb, ks == 0 ? pa0 : pa1, o[n], 0, 0, 0);
                }
            }
            __builtin_amdgcn_s_setprio(0);
        }

        __syncthreads();   // all reads done before next tile's staging
    }

    // epilogue: lane owns q=qrow, d = 16n+4lg+{0..3}
    const float linv = 1.f / l;
    unsigned short* orow = attn_out + ((size_t)b * T_ + qrow) * DIM_ + h * HD_;
    #pragma unroll
    for (int n = 0; n < 4; ++n) {
        unsigned short u[4];
        #pragma unroll
        for (int r = 0; r < 4; ++r) u[r] = f2bf(o[n][r] * linv);
        *(u16x4*)&orow[16 * n + 4 * lg] = *(u16x4*)u;
    }
}

// ---------------------------------------------------------------------------
// Kernel 3: output projection bf16 MFMA. d_out = attnb @ Wot^T (f32 out)
// ---------------------------------------------------------------------------
__global__ __launch_bounds__(256) void outproj_mfma_kernel(
    const unsigned short* __restrict__ Ab, const unsigned short* __restrict__ Wot,
    float* __restrict__ out)
{
    __shared__ __align__(16) unsigned char As[16384];
    __shared__ __align__(16) unsigned char Bs[16384];

    const int tid = threadIdx.x, lane = tid & 63, w = tid >> 6;
    const int lr = lane & 15, lg = lane >> 4;
    const int wm = w >> 1, wn = w & 1;
    const int bn = blockIdx.x, bm = blockIdx.y;
    const int m0 = bm * 128, n0 = bn * 128;

    const int chunkR = lane >> 3;
    const int srcOff = 8 * ((lane & 7) ^ chunkR);

    f32x4 acc[4][4] = {};

    for (int k0 = 0; k0 < 1024; k0 += 64) {
        __syncthreads();
        #pragma unroll
        for (int i = 0; i < 4; ++i) {
            const int chunk = w * 4 + i;
            const int row = chunk * 8 + chunkR;
            gload16(Ab  + (size_t)(m0 + row) * 1024 + k0 + srcOff, As + chunk * 1024);
            gload16(Wot + (size_t)(n0 + row) * 1024 + k0 + srcOff, Bs + chunk * 1024);
        }
        __syncthreads();
        #pragma unroll
        for (int kk = 0; kk < 2; ++kk) {
            bf16x8 af[4], bfr[4];
            #pragma unroll
            for (int mf = 0; mf < 4; ++mf) {
                const int row = wm * 64 + mf * 16 + lr;
                af[mf] = *(const bf16x8*)(As + row * 128 +
                          ((kk * 64 + lg * 16) ^ ((row & 7) << 4)));
            }
            #pragma unroll
            for (int nf = 0; nf < 4; ++nf) {
                const int row = wn * 64 + nf * 16 + lr;
                bfr[nf] = *(const bf16x8*)(Bs + row * 128 +
                          ((kk * 64 + lg * 16) ^ ((row & 7) << 4)));
            }
            #pragma unroll
            for (int mf = 0; mf < 4; ++mf)
                #pragma unroll
                for (int nf = 0; nf < 4; ++nf)
                    acc[mf][nf] = __builtin_amdgcn_mfma_f32_16x16x32_bf16(
                        af[mf], bfr[nf], acc[mf][nf], 0, 0, 0);
        }
    }

    #pragma unroll
    for (int nf = 0; nf < 4; ++nf) {
        const int col = n0 + wn * 64 + nf * 16 + lr;
        #pragma unroll
        for (int mf = 0; mf < 4; ++mf) {
            const int mrow = m0 + wm * 64 + mf * 16 + lg * 4;
            #pragma unroll
            for (int r = 0; r < 4; ++r)
                out[(size_t)(mrow + r) * 1024 + col] = acc[mf][nf][r];
        }
    }
}

// ---------------------------------------------------------------------------
extern "C" void kernel_launch(void* const* d_in, const int* in_sizes, int n_in,
                              void* d_out, int out_size, void* d_ws, size_t ws_size,
                              hipStream_t stream)
{
    const float* x     = (const float*)d_in[0];
    const float* sinp  = (const float*)d_in[1];
    const float* cosp  = (const float*)d_in[2];
    const float* maskp = (const float*)d_in[3];
    const float* Wq    = (const float*)d_in[4];
    const float* Wk    = (const float*)d_in[5];
    const float* Wv    = (const float*)d_in[6];
    const float* Wo    = (const float*)d_in[7];

    unsigned short* wsb = (unsigned short*)d_ws;
    unsigned short* xb  = wsb + XB_OFF;
    unsigned short* Wt  = wsb + WT_OFF;
    unsigned short* Wot = wsb + WOT_OFF;
    unsigned short* Qw  = wsb + QB_OFF;
    unsigned short* Kw  = wsb + KB_OFF;
    unsigned short* Vtw = wsb + VTB_OFF;
    unsigned short* Ab  = wsb + AB_OFF;
    float* out = (float*)d_out;

    cvt_kernel<<<2048, 256, 0, stream>>>(x, xb);
    wtrans_kernel<<<dim3(16, 16), 256, 0, stream>>>(Wq, Wt, 1024);
    wtrans_kernel<<<dim3(4, 16), 256, 0, stream>>>(Wk, Wt + 1024u * 1024u, 256);
    wtrans_kernel<<<dim3(4, 16), 256, 0, stream>>>(Wv, Wt + 1280u * 1024u, 256);
    wtrans_kernel<<<dim3(16, 16), 256, 0, stream>>>(Wo, Wot, 1024);

    qkv_mfma_kernel<<<dim3(12, 32), 256, 0, stream>>>(xb, Wt, sinp, cosp,
                                                      Qw, Kw, Vtw);
    attn_kernel<<<dim3(512), 512, 0, stream>>>(
        Qw, Kw, Vtw, maskp, Ab);
    outproj_mfma_kernel<<<dim3(8, 32), 256, 0, stream>>>(Ab, Wot, out);
}

// Round 11
// 116.816 us; speedup vs baseline: 1.4475x; 1.1776x over previous
//
#include <hip/hip_runtime.h>
#include <math.h>

typedef __attribute__((ext_vector_type(8))) short bf16x8;
typedef __attribute__((ext_vector_type(4))) float f32x4;
typedef __attribute__((ext_vector_type(4))) unsigned short u16x4;

#define B_    2
#define T_    2048
#define DIM_  1024
#define H_    16
#define KV_   4
#define HD_   64

// 1/sqrt(HD) * log2(e): folded into Q at projection time -> S is exp2-domain
#define QSCALE 0.1803368801111437f

static __device__ __forceinline__ unsigned short f2bf(float f) {
    union { float f; unsigned int u; } v; v.f = f;
    unsigned int r = v.u + 0x7fff + ((v.u >> 16) & 1);   // RNE
    return (unsigned short)(r >> 16);
}

// pack two f32 -> two bf16 (round-half-up): ~5 VALU, compiler-schedulable
static __device__ __forceinline__ unsigned int pkbf(float lo, float hi) {
    union { float f; unsigned int u; } a, b; a.f = lo; b.f = hi;
    return ((a.u + 0x8000u) >> 16) | ((b.u + 0x8000u) & 0xffff0000u);
}

static __device__ __forceinline__ void gload16(const void* g, void* l) {
    __builtin_amdgcn_global_load_lds(
        (const __attribute__((address_space(1))) unsigned int*)g,
        (__attribute__((address_space(3))) unsigned int*)l, 16, 0, 0);
}

// Workspace (unsigned short elements):
#define XB_OFF   0u
#define WT_OFF   4194304u
#define WOT_OFF  5767168u
#define QB_OFF   6815744u
#define KB_OFF   11010048u
#define VTB_OFF  12058624u
#define AB_OFF   13107200u

// ---------------------------------------------------------------------------
__global__ __launch_bounds__(256) void cvt_kernel(
    const float* __restrict__ in, unsigned short* __restrict__ out)
{
    const size_t i = ((size_t)blockIdx.x * 256 + threadIdx.x) * 8;
    float4 a = *(const float4*)&in[i];
    float4 b = *(const float4*)&in[i + 4];
    unsigned short u[8] = {f2bf(a.x), f2bf(a.y), f2bf(a.z), f2bf(a.w),
                           f2bf(b.x), f2bf(b.y), f2bf(b.z), f2bf(b.w)};
    *(bf16x8*)&out[i] = *(bf16x8*)u;
}

// ---------------------------------------------------------------------------
__global__ __launch_bounds__(256) void wtrans_kernel(
    const float* __restrict__ W, unsigned short* __restrict__ Wt, int N)
{
    __shared__ float Ts[64][65];
    const int n0 = blockIdx.x * 64, k0 = blockIdx.y * 64;
    const int tid = threadIdx.x;
    const int r = tid >> 4, c4 = (tid & 15) * 4;
    #pragma unroll
    for (int i = 0; i < 4; ++i) {
        float4 v = *(const float4*)&W[(size_t)(k0 + r + 16 * i) * N + n0 + c4];
        Ts[r + 16 * i][c4 + 0] = v.x; Ts[r + 16 * i][c4 + 1] = v.y;
        Ts[r + 16 * i][c4 + 2] = v.z; Ts[r + 16 * i][c4 + 3] = v.w;
    }
    __syncthreads();
    const int rn = tid >> 3, ck = (tid & 7) * 8;
    #pragma unroll
    for (int i = 0; i < 2; ++i) {
        int n = rn + 32 * i;
        unsigned short u[8];
        #pragma unroll
        for (int e = 0; e < 8; ++e) u[e] = f2bf(Ts[ck + e][n]);
        *(bf16x8*)&Wt[(size_t)(n0 + n) * 1024 + k0 + ck] = *(bf16x8*)u;
    }
}

// ---------------------------------------------------------------------------
// Kernel 1: QKV bf16 MFMA GEMM + RoPE epilogue.  64x128 tile, BK=64,
// grid (12,64) = 768 blocks (3/CU), 4 waves: wave = 32 rows x 64 cols.
// ---------------------------------------------------------------------------
__global__ __launch_bounds__(256) void qkv_mfma_kernel(
    const unsigned short* __restrict__ xb, const unsigned short* __restrict__ Wt,
    const float* __restrict__ sinp, const float* __restrict__ cosp,
    unsigned short* __restrict__ Qw, unsigned short* __restrict__ Kw,
    unsigned short* __restrict__ Vtw)
{
    __shared__ __align__(16) unsigned char As[8192];    // [64 m][128B], swizzled
    __shared__ __align__(16) unsigned char Bs[16384];   // [128 n][128B]

    const int tid = threadIdx.x, lane = tid & 63, w = tid >> 6;
    const int lr = lane & 15, lg = lane >> 4;
    const int wm = w >> 1, wn = w & 1;
    const int bn = blockIdx.x, bm = blockIdx.y;
    const int m0 = bm * 64, n0 = bn * 128;

    const int chunkR = lane >> 3;
    const int srcOff = 8 * ((lane & 7) ^ chunkR);

    f32x4 acc[2][4] = {};

    for (int k0 = 0; k0 < 1024; k0 += 64) {
        __syncthreads();
        #pragma unroll
        for (int i = 0; i < 6; ++i) {
            const int c = w * 6 + i;
            if (c < 8) {
                const int row = c * 8 + chunkR;
                gload16(xb + (size_t)(m0 + row) * 1024 + k0 + srcOff, As + c * 1024);
            } else {
                const int row = (c - 8) * 8 + chunkR;
                gload16(Wt + (size_t)(n0 + row) * 1024 + k0 + srcOff,
                        Bs + (c - 8) * 1024);
            }
        }
        __syncthreads();
        #pragma unroll
        for (int kk = 0; kk < 2; ++kk) {
            bf16x8 af[2], bfr[4];
            #pragma unroll
            for (int mf = 0; mf < 2; ++mf) {
                const int row = wm * 32 + mf * 16 + lr;
                af[mf] = *(const bf16x8*)(As + row * 128 +
                          ((kk * 64 + lg * 16) ^ ((row & 7) << 4)));
            }
            #pragma unroll
            for (int nf = 0; nf < 4; ++nf) {
                const int row = wn * 64 + nf * 16 + lr;
                bfr[nf] = *(const bf16x8*)(Bs + row * 128 +
                          ((kk * 64 + lg * 16) ^ ((row & 7) << 4)));
            }
            #pragma unroll
            for (int mf = 0; mf < 2; ++mf)
                #pragma unroll
                for (int nf = 0; nf < 4; ++nf)
                    acc[mf][nf] = __builtin_amdgcn_mfma_f32_16x16x32_bf16(
                        af[mf], bfr[nf], acc[mf][nf], 0, 0, 0);
        }
    }

    const float rsign = (lane & 1) ? 1.f : -1.f;
    #pragma unroll
    for (int nf = 0; nf < 4; ++nf) {
        const int col = n0 + wn * 64 + nf * 16 + lr;
        #pragma unroll
        for (int mf = 0; mf < 2; ++mf) {
            const int mrow = m0 + wm * 32 + mf * 16 + lg * 4;
            const int b = mrow >> 11;
            const int t0 = mrow & 2047;
            if (col < 1280) {   // Q or K: RoPE
                const int d = col & 63;
                #pragma unroll
                for (int r = 0; r < 4; ++r) {
                    float val = acc[mf][nf][r];
                    float partner = __shfl_xor(val, 1);
                    const int t = t0 + r;
                    float cs = cosp[t * 64 + d], sn = sinp[t * 64 + d];
                    float rv = val * cs + rsign * partner * sn;
                    if (col < 1024) {
                        const int h = col >> 6;
                        Qw[(((size_t)b * H_ + h) * T_ + t) * 64 + d] =
                            f2bf(rv * QSCALE);
                    } else {
                        const int kv = (col - 1024) >> 6;
                        char* krow = (char*)Kw +
                            ((((size_t)b * KV_ + kv) * T_ + t) << 7);
                        *(unsigned short*)(krow + ((2 * d) ^ ((t & 7) << 4))) =
                            f2bf(rv);
                    }
                }
            } else {            // V: transposed swizzled store, 4 t packed
                const int cv = col - 1280, kv = cv >> 6, d = cv & 63;
                unsigned short u[4];
                #pragma unroll
                for (int r = 0; r < 4; ++r) u[r] = f2bf(acc[mf][nf][r]);
                char* vrow = (char*)Vtw +
                    ((((size_t)b * KV_ + kv) * 64 + d) * (size_t)T_ * 2);
                *(u16x4*)(vrow + ((2 * t0) ^ ((d & 7) << 4))) = *(u16x4*)u;
            }
        }
    }
}

// ---------------------------------------------------------------------------
// Kernel 2: causal GQA flash attention (R10 structure + VALU diet).
// Block = 512 thr = 8 waves; waves 0-3: qtA=31-p, waves 4-7: qtB=p, shared
// staging loop. Mask pre-converted to additive bias in LDS. Round-half-up
// P pack; tree reductions.
// ---------------------------------------------------------------------------
__global__ __launch_bounds__(512, 4) void attn_kernel(
    const unsigned short* __restrict__ Qg, const unsigned short* __restrict__ Kg,
    const unsigned short* __restrict__ Vtg, const float* __restrict__ maskp,
    unsigned short* __restrict__ attn_out)
{
    __shared__ __align__(16) unsigned char Kl[8192];      // [key][d], swizzled
    __shared__ __align__(16) unsigned char Vl[8192];      // [d][key], swizzled
    __shared__ __align__(16) unsigned char Pl[8][2048];   // per-wave P^T
    __shared__ __align__(16) float Ml[2048];              // additive mask bias

    const int tid  = threadIdx.x;
    const int lane = tid & 63;
    const int w    = tid >> 6;             // 0..7
    const int grp  = w >> 2;
    const int wq   = w & 3;
    const int lr   = lane & 15;
    const int lg   = lane >> 4;

    const int bi   = blockIdx.x;
    const int half = bi >> 8;
    const int j    = bi & 255;
    const int bh   = j >> 3;
    const int idx  = j & 7;
    const int p    = half ? (15 - idx) : idx;
    const int qtA  = 31 - p;
    const int qt   = grp ? p : qtA;
    const int h    = bh & 15;
    const int b    = bh >> 4;
    const int kvh  = h >> 2;
    const int q0   = qt * 64;
    const int qrow = q0 + wq * 16 + lr;

    const char* Kb = (const char*)(Kg  + ((size_t)b * KV_ + kvh) * T_ * HD_);
    const char* Vb = (const char*)(Vtg + ((size_t)b * KV_ + kvh) * HD_ * T_);

    // mask -> additive bias in LDS (one float4 per thread)
    {
        f32x4 mv4 = *(const f32x4*)&maskp[b * T_ + tid * 4];
        f32x4 bv;
        #pragma unroll
        for (int e = 0; e < 4; ++e) bv[e] = mv4[e] > 0.f ? 0.f : -1e30f;
        *(f32x4*)&Ml[tid * 4] = bv;
    }

    const int sr  = lane >> 3;
    const int scb = (lane & 7) * 16;
    unsigned char* Pw = &Pl[w][0];

    const unsigned short* Qbase =
        Qg + (((size_t)b * H_ + h) * T_ + qrow) * HD_;
    const bf16x8 qf0 = *(const bf16x8*)(Qbase + lg * 8);
    const bf16x8 qf1 = *(const bf16x8*)(Qbase + 32 + lg * 8);

    f32x4 o[4] = {};
    float m = -1e30f, l = 0.f;

    for (int kt = 0; kt <= qtA; ++kt) {
        const int k0 = kt * 64;

        {
            const int row = w * 8 + sr;
            gload16(Kb + (size_t)(k0 + row) * 128 + scb, &Kl[w * 1024]);
            gload16(Vb + (size_t)row * 4096 + 2 * k0 + scb, &Vl[w * 1024]);
        }
        __syncthreads();   // staging (and Ml on kt=0) landed

        if (kt <= qt) {
            // QK^T transposed: s[n][r] = S[key=k0+16n+4lg+r][q=qrow]
            f32x4 s[4] = {};
            __builtin_amdgcn_s_setprio(1);
            #pragma unroll
            for (int n = 0; n < 4; ++n) {
                const int key = 16 * n + lr;
                #pragma unroll
                for (int ks = 0; ks < 2; ++ks) {
                    bf16x8 kb = *(const bf16x8*)(Kl +
                        ((key * 128 + 64 * ks + lg * 16) ^ ((key & 7) << 4)));
                    s[n] = __builtin_amdgcn_mfma_f32_16x16x32_bf16(
                        kb, ks == 0 ? qf0 : qf1, s[n], 0, 0, 0);
                }
            }
            __builtin_amdgcn_s_setprio(0);

            // additive mask bias (+ causal on diagonal tile)
            if (kt == qt) {
                #pragma unroll
                for (int n = 0; n < 4; ++n) {
                    f32x4 bv = *(const f32x4*)&Ml[k0 + 16 * n + 4 * lg];
                    #pragma unroll
                    for (int r = 0; r < 4; ++r) {
                        const int keyg = k0 + 16 * n + 4 * lg + r;
                        s[n][r] = (keyg <= qrow) ? s[n][r] + bv[r] : -1e30f;
                    }
                }
            } else {
                #pragma unroll
                for (int n = 0; n < 4; ++n) {
                    f32x4 bv = *(const f32x4*)&Ml[k0 + 16 * n + 4 * lg];
                    #pragma unroll
                    for (int r = 0; r < 4; ++r) s[n][r] += bv[r];
                }
            }

            // online softmax, exp2-domain; tree reductions
            float tmax[4];
            #pragma unroll
            for (int n = 0; n < 4; ++n)
                tmax[n] = fmaxf(fmaxf(s[n][0], s[n][1]), fmaxf(s[n][2], s[n][3]));
            float mx = fmaxf(fmaxf(tmax[0], tmax[1]), fmaxf(tmax[2], tmax[3]));
            mx = fmaxf(mx, __shfl_xor(mx, 16));
            mx = fmaxf(mx, __shfl_xor(mx, 32));
            const float mnew = fmaxf(m, mx);
            const float alpha = exp2f(m - mnew);
            m = mnew;
            #pragma unroll
            for (int n = 0; n < 4; ++n)
                #pragma unroll
                for (int r = 0; r < 4; ++r)
                    s[n][r] = exp2f(s[n][r] - mnew);
            float tsum[4];
            #pragma unroll
            for (int n = 0; n < 4; ++n)
                tsum[n] = (s[n][0] + s[n][1]) + (s[n][2] + s[n][3]);
            float rsum = (tsum[0] + tsum[1]) + (tsum[2] + tsum[3]);
            rsum += __shfl_xor(rsum, 16);
            rsum += __shfl_xor(rsum, 32);
            l = l * alpha + rsum;
            #pragma unroll
            for (int n = 0; n < 4; ++n) o[n] *= alpha;

            // P^T -> wave-private LDS (round-half-up pack)
            #pragma unroll
            for (int n = 0; n < 4; ++n) {
                uint2 wv;
                wv.x = pkbf(s[n][0], s[n][1]);
                wv.y = pkbf(s[n][2], s[n][3]);
                *(uint2*)(Pw + ((lr * 128 + 32 * n + 8 * lg) ^ ((lr & 7) << 4))) = wv;
            }
            bf16x8 pa0 = *(const bf16x8*)(Pw + ((lr * 128 +      lg * 16) ^ ((lr & 7) << 4)));
            bf16x8 pa1 = *(const bf16x8*)(Pw + ((lr * 128 + 64 + lg * 16) ^ ((lr & 7) << 4)));

            // PV transposed: o[n][r] = O[q=qrow][d=16n+4lg+r]
            __builtin_amdgcn_s_setprio(1);
            #pragma unroll
            for (int n = 0; n < 4; ++n) {
                const int d = 16 * n + lr;
                #pragma unroll
                for (int ks = 0; ks < 2; ++ks) {
                    bf16x8 vb = *(const bf16x8*)(Vl +
                        ((d * 128 + 64 * ks + lg * 16) ^ ((d & 7) << 4)));
                    o[n] = __builtin_amdgcn_mfma_f32_16x16x32_bf16(
                        vb, ks == 0 ? pa0 : pa1, o[n], 0, 0, 0);
                }
            }
            __builtin_amdgcn_s_setprio(0);
        }

        __syncthreads();
    }

    const float linv = 1.f / l;
    unsigned short* orow = attn_out + ((size_t)b * T_ + qrow) * DIM_ + h * HD_;
    #pragma unroll
    for (int n = 0; n < 4; ++n) {
        unsigned short u[4];
        #pragma unroll
        for (int r = 0; r < 4; ++r) u[r] = f2bf(o[n][r] * linv);
        *(u16x4*)&orow[16 * n + 4 * lg] = *(u16x4*)u;
    }
}

// ---------------------------------------------------------------------------
// Kernel 3: output projection bf16 MFMA. 64x128 tile, grid (8,64) = 512 blocks.
// ---------------------------------------------------------------------------
__global__ __launch_bounds__(256) void outproj_mfma_kernel(
    const unsigned short* __restrict__ Ab, const unsigned short* __restrict__ Wot,
    float* __restrict__ out)
{
    __shared__ __align__(16) unsigned char As[8192];
    __shared__ __align__(16) unsigned char Bs[16384];

    const int tid = threadIdx.x, lane = tid & 63, w = tid >> 6;
    const int lr = lane & 15, lg = lane >> 4;
    const int wm = w >> 1, wn = w & 1;
    const int bn = blockIdx.x, bm = blockIdx.y;
    const int m0 = bm * 64, n0 = bn * 128;

    const int chunkR = lane >> 3;
    const int srcOff = 8 * ((lane & 7) ^ chunkR);

    f32x4 acc[2][4] = {};

    for (int k0 = 0; k0 < 1024; k0 += 64) {
        __syncthreads();
        #pragma unroll
        for (int i = 0; i < 6; ++i) {
            const int c = w * 6 + i;
            if (c < 8) {
                const int row = c * 8 + chunkR;
                gload16(Ab + (size_t)(m0 + row) * 1024 + k0 + srcOff, As + c * 1024);
            } else {
                const int row = (c - 8) * 8 + chunkR;
                gload16(Wot + (size_t)(n0 + row) * 1024 + k0 + srcOff,
                        Bs + (c - 8) * 1024);
            }
        }
        __syncthreads();
        #pragma unroll
        for (int kk = 0; kk < 2; ++kk) {
            bf16x8 af[2], bfr[4];
            #pragma unroll
            for (int mf = 0; mf < 2; ++mf) {
                const int row = wm * 32 + mf * 16 + lr;
                af[mf] = *(const bf16x8*)(As + row * 128 +
                          ((kk * 64 + lg * 16) ^ ((row & 7) << 4)));
            }
            #pragma unroll
            for (int nf = 0; nf < 4; ++nf) {
                const int row = wn * 64 + nf * 16 + lr;
                bfr[nf] = *(const bf16x8*)(Bs + row * 128 +
                          ((kk * 64 + lg * 16) ^ ((row & 7) << 4)));
            }
            #pragma unroll
            for (int mf = 0; mf < 2; ++mf)
                #pragma unroll
                for (int nf = 0; nf < 4; ++nf)
                    acc[mf][nf] = __builtin_amdgcn_mfma_f32_16x16x32_bf16(
                        af[mf], bfr[nf], acc[mf][nf], 0, 0, 0);
        }
    }

    #pragma unroll
    for (int nf = 0; nf < 4; ++nf) {
        const int col = n0 + wn * 64 + nf * 16 + lr;
        #pragma unroll
        for (int mf = 0; mf < 2; ++mf) {
            const int mrow = m0 + wm * 32 + mf * 16 + lg * 4;
            #pragma unroll
            for (int r = 0; r < 4; ++r)
                out[(size_t)(mrow + r) * 1024 + col] = acc[mf][nf][r];
        }
    }
}

// ---------------------------------------------------------------------------
extern "C" void kernel_launch(void* const* d_in, const int* in_sizes, int n_in,
                              void* d_out, int out_size, void* d_ws, size_t ws_size,
                              hipStream_t stream)
{
    const float* x     = (const float*)d_in[0];
    const float* sinp  = (const float*)d_in[1];
    const float* cosp  = (const float*)d_in[2];
    const float* maskp = (const float*)d_in[3];
    const float* Wq    = (const float*)d_in[4];
    const float* Wk    = (const float*)d_in[5];
    const float* Wv    = (const float*)d_in[6];
    const float* Wo    = (const float*)d_in[7];

    unsigned short* wsb = (unsigned short*)d_ws;
    unsigned short* xb  = wsb + XB_OFF;
    unsigned short* Wt  = wsb + WT_OFF;
    unsigned short* Wot = wsb + WOT_OFF;
    unsigned short* Qw  = wsb + QB_OFF;
    unsigned short* Kw  = wsb + KB_OFF;
    unsigned short* Vtw = wsb + VTB_OFF;
    unsigned short* Ab  = wsb + AB_OFF;
    float* out = (float*)d_out;

    cvt_kernel<<<2048, 256, 0, stream>>>(x, xb);
    wtrans_kernel<<<dim3(16, 16), 256, 0, stream>>>(Wq, Wt, 1024);
    wtrans_kernel<<<dim3(4, 16), 256, 0, stream>>>(Wk, Wt + 1024u * 1024u, 256);
    wtrans_kernel<<<dim3(4, 16), 256, 0, stream>>>(Wv, Wt + 1280u * 1024u, 256);
    wtrans_kernel<<<dim3(16, 16), 256, 0, stream>>>(Wo, Wot, 1024);

    qkv_mfma_kernel<<<dim3(12, 64), 256, 0, stream>>>(xb, Wt, sinp, cosp,
                                                      Qw, Kw, Vtw);
    attn_kernel<<<dim3(512), 512, 0, stream>>>(
        Qw, Kw, Vtw, maskp, Ab);
    outproj_mfma_kernel<<<dim3(8, 64), 256, 0, stream>>>(Ab, Wot, out);
}